// Round 1
// baseline (692.481 us; speedup 1.0000x reference)
//
#include <hip/hip_runtime.h>

// NuclearLossFunc: loss = sum(x^2) / (B*C), B*C = 32*64 = 2048.
// Pure HBM-streaming reduction over 512 MiB fp32.

__global__ __launch_bounds__(256) void nuclear_loss_kernel(
    const float4* __restrict__ in, float* __restrict__ out,
    long long n4, float scale)
{
    long long idx    = (long long)blockIdx.x * blockDim.x + threadIdx.x;
    long long stride = (long long)gridDim.x * blockDim.x;

    float acc = 0.0f;
    for (long long i = idx; i < n4; i += stride) {
        float4 v = in[i];
        acc += v.x * v.x + v.y * v.y + v.z * v.z + v.w * v.w;
    }

    // wave-64 reduction
    #pragma unroll
    for (int off = 32; off > 0; off >>= 1)
        acc += __shfl_down(acc, off, 64);

    __shared__ float smem[4];
    int lane = threadIdx.x & 63;
    int wave = threadIdx.x >> 6;
    if (lane == 0) smem[wave] = acc;
    __syncthreads();

    if (threadIdx.x == 0) {
        float s = smem[0] + smem[1] + smem[2] + smem[3];
        atomicAdd(out, s * scale);  // device-scope by default on CDNA
    }
}

extern "C" void kernel_launch(void* const* d_in, const int* in_sizes, int n_in,
                              void* d_out, int out_size, void* d_ws, size_t ws_size,
                              hipStream_t stream) {
    const float* in = (const float*)d_in[0];
    float* out = (float*)d_out;

    long long n  = (long long)in_sizes[0];   // 32*64*256*256 = 134217728
    long long n4 = n / 4;                    // divisible by 4
    const float scale = 1.0f / 2048.0f;      // 1/(B*C)

    // d_out is poisoned with 0xAA before every timed launch — zero it.
    hipMemsetAsync(d_out, 0, (size_t)out_size * sizeof(float), stream);

    const int block = 256;
    const int grid  = 8192;  // 32 blocks/CU worth of work; each thread sums ~16 float4s
    nuclear_loss_kernel<<<grid, block, 0, stream>>>(
        (const float4*)in, out, n4, scale);
}